// Round 1
// baseline (246.603 us; speedup 1.0000x reference)
//
#include <hip/hip_runtime.h>

// Problem constants
#define B_  4
#define T_  2048
#define C_  1024
#define HS_ 64
#define M_  (B_*T_)   // 8192 rows
#define NCAT 192      // 3*HS concatenated q,k,v output cols

typedef unsigned short ushort_t;
typedef short bf16x8 __attribute__((ext_vector_type(8)));   // 8 bf16 in 4 VGPRs
typedef float f32x4 __attribute__((ext_vector_type(4)));

static __device__ __forceinline__ unsigned short f2bf(float f) {
    union { float f; unsigned int u; } c; c.f = f;
    unsigned int u = c.u;
    unsigned int r = (u + 0x7FFFu + ((u >> 16) & 1u)) >> 16;  // RNE
    return (unsigned short)r;
}

// ---------------------------------------------------------------------------
// Kernel 1: convert Wq|Wk|Wv (fp32, [C][HS] each) -> Wt bf16 transposed [192][1024]
// ---------------------------------------------------------------------------
__global__ void wconv_kernel(const float* __restrict__ Wq, const float* __restrict__ Wk,
                             const float* __restrict__ Wv, ushort_t* __restrict__ wt) {
    int idx = blockIdx.x * 256 + threadIdx.x;   // < 192*1024
    int n = idx >> 10;        // output col 0..191
    int k = idx & 1023;       // reduction index
    const float* W = (n < 64) ? Wq : (n < 128) ? Wk : Wv;
    wt[idx] = f2bf(W[k * HS_ + (n & 63)]);
}

// ---------------------------------------------------------------------------
// Kernel 2: QKV projection. One wave = 16 rows x 192 cols, K-loop of 32.
// A-frags straight from global x (cvt fp32->bf16), B-frags 16B from Wt (L1/L2).
// ---------------------------------------------------------------------------
__global__ __launch_bounds__(128) void proj_kernel(const float* __restrict__ x,
    const ushort_t* __restrict__ wt,
    ushort_t* __restrict__ qws, ushort_t* __restrict__ kws, ushort_t* __restrict__ vws) {
    int tid  = threadIdx.x;
    int wid  = tid >> 6;
    int lane = tid & 63;
    int quad = lane >> 4;
    int lq   = lane & 15;
    int r0   = (blockIdx.x * 2 + wid) * 16;     // 512 waves cover 8192 rows

    f32x4 acc[12];
    #pragma unroll
    for (int i = 0; i < 12; i++) acc[i] = (f32x4){0.f, 0.f, 0.f, 0.f};

    for (int k0 = 0; k0 < C_; k0 += 32) {
        const float* xp = x + (size_t)(r0 + lq) * C_ + k0 + quad * 8;
        float4 a0 = *(const float4*)xp;
        float4 a1 = *(const float4*)(xp + 4);
        bf16x8 af;
        af[0] = (short)f2bf(a0.x); af[1] = (short)f2bf(a0.y);
        af[2] = (short)f2bf(a0.z); af[3] = (short)f2bf(a0.w);
        af[4] = (short)f2bf(a1.x); af[5] = (short)f2bf(a1.y);
        af[6] = (short)f2bf(a1.z); af[7] = (short)f2bf(a1.w);
        #pragma unroll
        for (int nt = 0; nt < 12; nt++) {
            bf16x8 bfv = *(const bf16x8*)(wt + (size_t)(nt * 16 + lq) * C_ + k0 + quad * 8);
            acc[nt] = __builtin_amdgcn_mfma_f32_16x16x32_bf16(af, bfv, acc[nt], 0, 0, 0);
        }
    }

    // Epilogue: C/D layout row=quad*4+r, col=lq. Write bf16 Q/K/V.
    #pragma unroll
    for (int nt = 0; nt < 12; nt++) {
        int n = nt * 16 + lq;
        ushort_t* dst = (n < 64) ? qws : (n < 128) ? kws : vws;
        int nn = n & 63;
        #pragma unroll
        for (int r = 0; r < 4; r++) {
            int row = r0 + quad * 4 + r;
            dst[(size_t)row * HS_ + nn] = f2bf(acc[nt][r]);
        }
    }
}

// ---------------------------------------------------------------------------
// Kernel 3: causal flash attention. Block = 2 waves = 32 q-rows; key tiles of 32.
// ---------------------------------------------------------------------------
__global__ __launch_bounds__(128) void flash_kernel(const ushort_t* __restrict__ qws,
    const ushort_t* __restrict__ kws, const ushort_t* __restrict__ vws,
    float* __restrict__ out) {
    __shared__ __align__(16) ushort_t Ks[32 * 64];      // [key][d]
    __shared__ __align__(16) ushort_t Vt[64 * 32];      // [d][key] (transposed)
    __shared__ __align__(16) ushort_t Pw[2][16 * 32];   // per-wave P staging

    int tid  = threadIdx.x;
    int wid  = tid >> 6;
    int lane = tid & 63;
    int quad = lane >> 4;
    int lq   = lane & 15;

    int batch = blockIdx.x >> 6;   // 4 batches
    int tile  = blockIdx.x & 63;   // 64 q-tiles of 32 per batch
    int q0    = tile * 32;
    int rowbase = batch * T_ + q0 + wid * 16;   // this wave's first global q row

    // Q A-frags: A[m=lq][k=quad*8+j], two k-steps covering d=0..63
    bf16x8 qf[2];
    #pragma unroll
    for (int st = 0; st < 2; st++)
        qf[st] = *(const bf16x8*)(qws + (size_t)(rowbase + lq) * HS_ + st * 32 + quad * 8);

    float m_run[4], l_run[4];
    f32x4 O[4];
    #pragma unroll
    for (int r = 0; r < 4; r++) { m_run[r] = -INFINITY; l_run[r] = 0.f; }
    #pragma unroll
    for (int nt = 0; nt < 4; nt++) O[nt] = (f32x4){0.f, 0.f, 0.f, 0.f};

    const float scale = 0.03125f;   // C^-0.5
    int nkt = tile + 1;             // causal: keys up to q0+31

    for (int kt = 0; kt < nkt; kt++) {
        int keybase = batch * T_ + kt * 32;
        {   // stage K row-major, V transposed
            int row  = tid >> 2;          // 0..31 (key)
            int cseg = (tid & 3) * 16;    // d segment
            const float4* kp = (const float4*)(kws + (size_t)(keybase + row) * HS_ + cseg);
            float4 k0v = kp[0], k1v = kp[1];
            float4* ksd = (float4*)(Ks + row * 64 + cseg);
            ksd[0] = k0v; ksd[1] = k1v;
            union { float4 f4[2]; ushort_t u[16]; } vv;
            const float4* vp = (const float4*)(vws + (size_t)(keybase + row) * HS_ + cseg);
            vv.f4[0] = vp[0]; vv.f4[1] = vp[1];
            #pragma unroll
            for (int u = 0; u < 16; u++) Vt[(cseg + u) * 32 + row] = vv.u[u];
        }
        __syncthreads();

        // S = (Q K^T) * scale, causal-masked. D layout: row=quad*4+r (q), col=lq (key)
        f32x4 S[2];
        #pragma unroll
        for (int sub = 0; sub < 2; sub++) {
            f32x4 s = (f32x4){0.f, 0.f, 0.f, 0.f};
            #pragma unroll
            for (int st = 0; st < 2; st++) {
                bf16x8 kf = *(const bf16x8*)(Ks + (sub * 16 + lq) * 64 + st * 32 + quad * 8);
                s = __builtin_amdgcn_mfma_f32_16x16x32_bf16(qf[st], kf, s, 0, 0, 0);
            }
            int kcol = kt * 32 + sub * 16 + lq;   // key index within batch
            #pragma unroll
            for (int r = 0; r < 4; r++) {
                int qrow = q0 + wid * 16 + quad * 4 + r;
                float sv = s[r] * scale;
                s[r] = (kcol <= qrow) ? sv : -INFINITY;
            }
            S[sub] = s;
        }

        // online softmax per q-row (row lives across the 16 lanes of a quad)
        #pragma unroll
        for (int r = 0; r < 4; r++) {
            float mx = fmaxf(S[0][r], S[1][r]);
            #pragma unroll
            for (int off = 1; off < 16; off <<= 1)
                mx = fmaxf(mx, __shfl_xor(mx, off, 64));
            float m_new = fmaxf(m_run[r], mx);
            float alpha = __expf(m_run[r] - m_new);
            float p0 = __expf(S[0][r] - m_new);
            float p1 = __expf(S[1][r] - m_new);
            S[0][r] = p0; S[1][r] = p1;
            float sum = p0 + p1;
            #pragma unroll
            for (int off = 1; off < 16; off <<= 1)
                sum += __shfl_xor(sum, off, 64);
            l_run[r] = l_run[r] * alpha + sum;
            m_run[r] = m_new;
            #pragma unroll
            for (int nt = 0; nt < 4; nt++) O[nt][r] *= alpha;
        }

        // P: C-layout -> LDS -> A-layout (verified round-trip pattern)
        #pragma unroll
        for (int sub = 0; sub < 2; sub++)
            #pragma unroll
            for (int r = 0; r < 4; r++)
                Pw[wid][(quad * 4 + r) * 32 + sub * 16 + lq] = f2bf(S[sub][r]);
        __syncthreads();

        bf16x8 pf = *(const bf16x8*)(&Pw[wid][lq * 32 + quad * 8]);
        #pragma unroll
        for (int nt = 0; nt < 4; nt++) {
            bf16x8 vf = *(const bf16x8*)(Vt + (nt * 16 + lq) * 32 + quad * 8);
            O[nt] = __builtin_amdgcn_mfma_f32_16x16x32_bf16(pf, vf, O[nt], 0, 0, 0);
        }
        __syncthreads();   // protect Ks/Vt before next stage
    }

    // epilogue: O / l, fp32 out
    #pragma unroll
    for (int nt = 0; nt < 4; nt++) {
        #pragma unroll
        for (int r = 0; r < 4; r++) {
            int row = rowbase + quad * 4 + r;
            out[(size_t)row * HS_ + nt * 16 + lq] = O[nt][r] / l_run[r];
        }
    }
}

// ---------------------------------------------------------------------------
extern "C" void kernel_launch(void* const* d_in, const int* in_sizes, int n_in,
                              void* d_out, int out_size, void* d_ws, size_t ws_size,
                              hipStream_t stream) {
    const float* x  = (const float*)d_in[0];
    const float* Wq = (const float*)d_in[1];
    const float* Wk = (const float*)d_in[2];
    const float* Wv = (const float*)d_in[3];
    float* out = (float*)d_out;

    ushort_t* wt  = (ushort_t*)d_ws;          // 192*1024 bf16
    ushort_t* qws = wt + (size_t)NCAT * C_;   // 8192*64 bf16 each
    ushort_t* kws = qws + (size_t)M_ * HS_;
    ushort_t* vws = kws + (size_t)M_ * HS_;

    wconv_kernel<<<NCAT * C_ / 256, 256, 0, stream>>>(Wq, Wk, Wv, wt);
    proj_kernel<<<M_ / 32, 128, 0, stream>>>(x, wt, qws, kws, vws);
    flash_kernel<<<B_ * (T_ / 32), 128, 0, stream>>>(qws, kws, vws, out);
}

// Round 2
// 183.281 us; speedup vs baseline: 1.3455x; 1.3455x over previous
//
#include <hip/hip_runtime.h>

// Problem constants
#define B_  4
#define T_  2048
#define C_  1024
#define HS_ 64
#define M_  (B_*T_)   // 8192 rows
#define NCAT 192      // 3*HS concatenated q,k,v output cols

typedef unsigned short ushort_t;
typedef short bf16x8 __attribute__((ext_vector_type(8)));   // 8 bf16 in 4 VGPRs
typedef float f32x4 __attribute__((ext_vector_type(4)));

static __device__ __forceinline__ unsigned short f2bf(float f) {
    union { float f; unsigned int u; } c; c.f = f;
    unsigned int u = c.u;
    unsigned int r = (u + 0x7FFFu + ((u >> 16) & 1u)) >> 16;  // RNE
    return (unsigned short)r;
}

// ---------------------------------------------------------------------------
// Kernel 1: Wq|Wk|Wv (fp32 [C][HS]) -> Wt bf16 transposed [192][1024]
// ---------------------------------------------------------------------------
__global__ void wconv_kernel(const float* __restrict__ Wq, const float* __restrict__ Wk,
                             const float* __restrict__ Wv, ushort_t* __restrict__ wt) {
    int idx = blockIdx.x * 256 + threadIdx.x;   // < 192*1024
    int n = idx >> 10;
    int k = idx & 1023;
    const float* W = (n < 64) ? Wq : (n < 128) ? Wk : Wv;
    wt[idx] = f2bf(W[k * HS_ + (n & 63)]);
}

// ---------------------------------------------------------------------------
// Kernel 2: x fp32 -> xb bf16 (streaming, 8 elems/thread)
// ---------------------------------------------------------------------------
__global__ void xconv_kernel(const float* __restrict__ x, ushort_t* __restrict__ xb) {
    size_t i = ((size_t)blockIdx.x * 256 + threadIdx.x) * 8;
    float4 a = *(const float4*)(x + i);
    float4 b = *(const float4*)(x + i + 4);
    union { bf16x8 v; ushort_t u[8]; } o;
    o.u[0] = f2bf(a.x); o.u[1] = f2bf(a.y); o.u[2] = f2bf(a.z); o.u[3] = f2bf(a.w);
    o.u[4] = f2bf(b.x); o.u[5] = f2bf(b.y); o.u[6] = f2bf(b.z); o.u[7] = f2bf(b.w);
    *(bf16x8*)(xb + i) = o.v;
}

// ---------------------------------------------------------------------------
// Kernel 3: QKV projection. grid (256 rowgroups, 3 colgroups), block = 2 waves.
// Wave = 16 rows x 64 cols (one of Q/K/V). V written TRANSPOSED [b][d][t].
// ---------------------------------------------------------------------------
__global__ __launch_bounds__(128) void proj_kernel(const ushort_t* __restrict__ xb,
    const ushort_t* __restrict__ wt,
    ushort_t* __restrict__ qws, ushort_t* __restrict__ kws, ushort_t* __restrict__ vt) {
    int tid  = threadIdx.x;
    int wid  = tid >> 6;
    int lane = tid & 63;
    int quad = lane >> 4;
    int lq   = lane & 15;
    int r0   = (blockIdx.x * 2 + wid) * 16;   // 512 rowgroups of 16
    int cg   = blockIdx.y;                     // 0=Q 1=K 2=V

    f32x4 acc[4];
    #pragma unroll
    for (int i = 0; i < 4; i++) acc[i] = (f32x4){0.f, 0.f, 0.f, 0.f};

    const ushort_t* xp = xb + (size_t)(r0 + lq) * C_ + quad * 8;
    const ushort_t* wp = wt + (size_t)(cg * 64 + lq) * C_ + quad * 8;

    #pragma unroll 4
    for (int k0 = 0; k0 < C_; k0 += 32) {
        bf16x8 af = *(const bf16x8*)(xp + k0);
        #pragma unroll
        for (int nt = 0; nt < 4; nt++) {
            bf16x8 bfv = *(const bf16x8*)(wp + (size_t)nt * 16 * C_ + k0);
            acc[nt] = __builtin_amdgcn_mfma_f32_16x16x32_bf16(af, bfv, acc[nt], 0, 0, 0);
        }
    }

    #pragma unroll
    for (int nt = 0; nt < 4; nt++) {
        int n = nt * 16 + lq;   // 0..63 within this output
        #pragma unroll
        for (int r = 0; r < 4; r++) {
            int row = r0 + quad * 4 + r;
            ushort_t val = f2bf(acc[nt][r]);
            if (cg == 0)      qws[(size_t)row * HS_ + n] = val;
            else if (cg == 1) kws[(size_t)row * HS_ + n] = val;
            else {
                int b = row >> 11, t = row & 2047;
                vt[((size_t)b * 64 + n) * T_ + t] = val;   // transposed
            }
        }
    }
}

// ---------------------------------------------------------------------------
// Kernel 4: causal flash, key-split x2. Block = 2 waves = 32 q-rows.
// K/V frags read DIRECTLY from global (L1/L2); no staging, no __syncthreads.
// Writes unnormalized O + m + l partials.
// ---------------------------------------------------------------------------
__global__ __launch_bounds__(128) void flash_kernel(const ushort_t* __restrict__ qws,
    const ushort_t* __restrict__ kws, const ushort_t* __restrict__ vt,
    float* __restrict__ opart, float* __restrict__ mpart, float* __restrict__ lpart) {
    __shared__ __align__(16) ushort_t Pw[2][16 * 32];   // per-wave P staging

    int tid  = threadIdx.x;
    int wid  = tid >> 6;
    int lane = tid & 63;
    int quad = lane >> 4;
    int lq   = lane & 15;

    int batch = blockIdx.x >> 7;          // 4
    int rem   = blockIdx.x & 127;
    int tile  = rem >> 1;                 // 64 q-tiles of 32
    int s     = rem & 1;                  // key-split half
    int q0    = tile * 32;
    int rowbase = batch * T_ + q0 + wid * 16;

    int nkt = tile + 1;
    int h   = (nkt + 1) >> 1;
    int kt0 = s ? h : 0;
    int kt1 = s ? nkt : h;

    bf16x8 qf[2];
    #pragma unroll
    for (int st = 0; st < 2; st++)
        qf[st] = *(const bf16x8*)(qws + (size_t)(rowbase + lq) * HS_ + st * 32 + quad * 8);

    float m_run[4], l_run[4];
    f32x4 O[4];
    #pragma unroll
    for (int r = 0; r < 4; r++) { m_run[r] = -INFINITY; l_run[r] = 0.f; }
    #pragma unroll
    for (int nt = 0; nt < 4; nt++) O[nt] = (f32x4){0.f, 0.f, 0.f, 0.f};

    const float scale = 0.03125f;   // C^-0.5

    for (int kt = kt0; kt < kt1; kt++) {
        int keybase = batch * T_ + kt * 32;

        // S = (Q K^T) * scale, masked. D: row=quad*4+r (q), col=lq (key)
        f32x4 S[2];
        #pragma unroll
        for (int sub = 0; sub < 2; sub++) {
            f32x4 sv = (f32x4){0.f, 0.f, 0.f, 0.f};
            #pragma unroll
            for (int st = 0; st < 2; st++) {
                bf16x8 kf = *(const bf16x8*)(kws + (size_t)(keybase + sub * 16 + lq) * HS_ + st * 32 + quad * 8);
                sv = __builtin_amdgcn_mfma_f32_16x16x32_bf16(qf[st], kf, sv, 0, 0, 0);
            }
            int kcol = kt * 32 + sub * 16 + lq;
            #pragma unroll
            for (int r = 0; r < 4; r++) {
                int qrow = q0 + wid * 16 + quad * 4 + r;
                float x = sv[r] * scale;
                sv[r] = (kcol <= qrow) ? x : -INFINITY;
            }
            S[sub] = sv;
        }

        // online softmax per q-row (16 lanes of a quad hold one row)
        #pragma unroll
        for (int r = 0; r < 4; r++) {
            float mx = fmaxf(S[0][r], S[1][r]);
            #pragma unroll
            for (int off = 1; off < 16; off <<= 1)
                mx = fmaxf(mx, __shfl_xor(mx, off, 64));
            float m_new = fmaxf(m_run[r], mx);
            float alpha = __expf(m_run[r] - m_new);
            float p0 = __expf(S[0][r] - m_new);
            float p1 = __expf(S[1][r] - m_new);
            S[0][r] = p0; S[1][r] = p1;
            float sum = p0 + p1;
            #pragma unroll
            for (int off = 1; off < 16; off <<= 1)
                sum += __shfl_xor(sum, off, 64);
            l_run[r] = l_run[r] * alpha + sum;
            m_run[r] = m_new;
            #pragma unroll
            for (int nt = 0; nt < 4; nt++) O[nt][r] *= alpha;
        }

        // P: C-layout -> per-wave LDS -> A-layout (no cross-wave sharing)
        #pragma unroll
        for (int sub = 0; sub < 2; sub++)
            #pragma unroll
            for (int r = 0; r < 4; r++)
                Pw[wid][(quad * 4 + r) * 32 + sub * 16 + lq] = f2bf(S[sub][r]);

        bf16x8 pf = *(const bf16x8*)(&Pw[wid][lq * 32 + quad * 8]);
        #pragma unroll
        for (int nt = 0; nt < 4; nt++) {
            bf16x8 vf = *(const bf16x8*)(vt + ((size_t)batch * 64 + nt * 16 + lq) * T_ + kt * 32 + quad * 8);
            O[nt] = __builtin_amdgcn_mfma_f32_16x16x32_bf16(pf, vf, O[nt], 0, 0, 0);
        }
    }

    // write unnormalized partials
    #pragma unroll
    for (int nt = 0; nt < 4; nt++) {
        #pragma unroll
        for (int r = 0; r < 4; r++) {
            int row = rowbase + quad * 4 + r;
            opart[((size_t)s * M_ + row) * HS_ + nt * 16 + lq] = O[nt][r];
        }
    }
    if (lq == 0) {
        #pragma unroll
        for (int r = 0; r < 4; r++) {
            int row = rowbase + quad * 4 + r;
            mpart[(size_t)s * M_ + row] = m_run[r];
            lpart[(size_t)s * M_ + row] = l_run[r];
        }
    }
}

// ---------------------------------------------------------------------------
// Kernel 5: log-sum-exp combine of the two key-split halves. float4/thread.
// ---------------------------------------------------------------------------
__global__ void combine_kernel(const float* __restrict__ opart,
    const float* __restrict__ mpart, const float* __restrict__ lpart,
    float* __restrict__ out) {
    int idx = blockIdx.x * 256 + threadIdx.x;   // < 8192*16
    int row = idx >> 4;
    int d   = (idx & 15) << 2;
    float m0 = mpart[row],       m1 = mpart[M_ + row];
    float l0 = lpart[row],       l1 = lpart[M_ + row];
    float M  = fmaxf(m0, m1);
    float e0 = __expf(m0 - M),   e1 = __expf(m1 - M);
    float li = 1.f / (l0 * e0 + l1 * e1);
    float4 O0 = *(const float4*)(opart + (size_t)row * HS_ + d);
    float4 O1 = *(const float4*)(opart + (size_t)(M_ + row) * HS_ + d);
    float4 o;
    o.x = (O0.x * e0 + O1.x * e1) * li;
    o.y = (O0.y * e0 + O1.y * e1) * li;
    o.z = (O0.z * e0 + O1.z * e1) * li;
    o.w = (O0.w * e0 + O1.w * e1) * li;
    *(float4*)(out + (size_t)row * HS_ + d) = o;
}

// ---------------------------------------------------------------------------
extern "C" void kernel_launch(void* const* d_in, const int* in_sizes, int n_in,
                              void* d_out, int out_size, void* d_ws, size_t ws_size,
                              hipStream_t stream) {
    const float* x  = (const float*)d_in[0];
    const float* Wq = (const float*)d_in[1];
    const float* Wk = (const float*)d_in[2];
    const float* Wv = (const float*)d_in[3];
    float* out = (float*)d_out;

    ushort_t* wt  = (ushort_t*)d_ws;                  // 192*1024
    ushort_t* xb  = wt  + (size_t)NCAT * C_;          // 8192*1024
    ushort_t* qws = xb  + (size_t)M_ * C_;            // 8192*64
    ushort_t* kws = qws + (size_t)M_ * HS_;           // 8192*64
    ushort_t* vt  = kws + (size_t)M_ * HS_;           // 4*64*2048 (transposed V)
    float* opart  = (float*)(vt + (size_t)M_ * HS_);  // 2*8192*64
    float* mpart  = opart + (size_t)2 * M_ * HS_;     // 2*8192
    float* lpart  = mpart + (size_t)2 * M_;           // 2*8192

    wconv_kernel<<<NCAT * C_ / 256, 256, 0, stream>>>(Wq, Wk, Wv, wt);
    xconv_kernel<<<M_ * C_ / (256 * 8), 256, 0, stream>>>(x, xb);
    proj_kernel<<<dim3(M_ / 32, 3), 128, 0, stream>>>(xb, wt, qws, kws, vt);
    flash_kernel<<<B_ * 64 * 2, 128, 0, stream>>>(qws, kws, vt, opart, mpart, lpart);
    combine_kernel<<<M_ * 16 / 256, 256, 0, stream>>>(opart, mpart, lpart, out);
}

// Round 3
// 149.396 us; speedup vs baseline: 1.6507x; 1.2268x over previous
//
#include <hip/hip_runtime.h>
#include <math.h>

// Problem constants
#define B_  4
#define T_  2048
#define C_  1024
#define HS_ 64
#define M_  (B_*T_)   // 8192 rows
#define NCAT 192

typedef unsigned short ushort_t;
typedef short bf16x8 __attribute__((ext_vector_type(8)));
typedef float f32x4 __attribute__((ext_vector_type(4)));

static __device__ __forceinline__ unsigned short f2bf(float f) {
    union { float f; unsigned int u; } c; c.f = f;
    unsigned int u = c.u;
    unsigned int r = (u + 0x7FFFu + ((u >> 16) & 1u)) >> 16;  // RNE
    return (unsigned short)r;
}
static __device__ __forceinline__ float b2f(unsigned short u) {
    union { unsigned int u; float f; } c; c.u = ((unsigned int)u) << 16;
    return c.f;
}

// ---------------------------------------------------------------------------
// Kernel 1: Wq|Wk|Wv (fp32 [C][HS]) -> wt bf16 transposed [192][1024]
// ---------------------------------------------------------------------------
__global__ void wconv_kernel(const float* __restrict__ Wq, const float* __restrict__ Wk,
                             const float* __restrict__ Wv, ushort_t* __restrict__ wt) {
    int idx = blockIdx.x * 256 + threadIdx.x;
    int n = idx >> 10;
    int k = idx & 1023;
    const float* W = (n < 64) ? Wq : (n < 128) ? Wk : Wv;
    wt[idx] = f2bf(W[k * HS_ + (n & 63)]);
}

// ---------------------------------------------------------------------------
// Kernel 2: x fp32 -> xb bf16
// ---------------------------------------------------------------------------
__global__ void xconv_kernel(const float* __restrict__ x, ushort_t* __restrict__ xb) {
    size_t i = ((size_t)blockIdx.x * 256 + threadIdx.x) * 8;
    float4 a = *(const float4*)(x + i);
    float4 b = *(const float4*)(x + i + 4);
    union { bf16x8 v; ushort_t u[8]; } o;
    o.u[0] = f2bf(a.x); o.u[1] = f2bf(a.y); o.u[2] = f2bf(a.z); o.u[3] = f2bf(a.w);
    o.u[4] = f2bf(b.x); o.u[5] = f2bf(b.y); o.u[6] = f2bf(b.z); o.u[7] = f2bf(b.w);
    *(bf16x8*)(xb + i) = o.v;
}

// ---------------------------------------------------------------------------
// Kernel 3: QKV projection. grid (256 rowpairs, 6 colgroups of 32), block 128.
// Wave = 16 rows x 32 cols. V written TRANSPOSED [b][d][t].
// ---------------------------------------------------------------------------
__global__ __launch_bounds__(128) void proj_kernel(const ushort_t* __restrict__ xb,
    const ushort_t* __restrict__ wt,
    ushort_t* __restrict__ qws, ushort_t* __restrict__ kws, ushort_t* __restrict__ vt) {
    int tid  = threadIdx.x;
    int wid  = tid >> 6;
    int lane = tid & 63;
    int qd   = lane >> 4;
    int lq   = lane & 15;
    int r0   = (blockIdx.x * 2 + wid) * 16;
    int cg   = blockIdx.y;                    // 0..5, 32 cols each

    f32x4 acc[2];
    acc[0] = (f32x4){0.f,0.f,0.f,0.f};
    acc[1] = (f32x4){0.f,0.f,0.f,0.f};

    const ushort_t* xp = xb + (size_t)(r0 + lq) * C_ + qd * 8;
    const ushort_t* wp = wt + (size_t)(cg * 32 + lq) * C_ + qd * 8;

    #pragma unroll 8
    for (int k0 = 0; k0 < C_; k0 += 32) {
        bf16x8 af = *(const bf16x8*)(xp + k0);
        bf16x8 b0 = *(const bf16x8*)(wp + k0);
        bf16x8 b1 = *(const bf16x8*)(wp + (size_t)16 * C_ + k0);
        acc[0] = __builtin_amdgcn_mfma_f32_16x16x32_bf16(af, b0, acc[0], 0, 0, 0);
        acc[1] = __builtin_amdgcn_mfma_f32_16x16x32_bf16(af, b1, acc[1], 0, 0, 0);
    }

    #pragma unroll
    for (int nt = 0; nt < 2; nt++) {
        int n = cg * 32 + nt * 16 + lq;   // 0..191
        int sel = n >> 6, nn = n & 63;
        #pragma unroll
        for (int r = 0; r < 4; r++) {
            int row = r0 + qd * 4 + r;
            ushort_t val = f2bf(acc[nt][r]);
            if (sel == 0)      qws[(size_t)row * HS_ + nn] = val;
            else if (sel == 1) kws[(size_t)row * HS_ + nn] = val;
            else {
                int b = row >> 11, t = row & 2047;
                vt[((size_t)b * 64 + nn) * T_ + t] = val;
            }
        }
    }
}

// ---------------------------------------------------------------------------
// Kernel 4: causal flash, transposed-S, chunked keys (KW=4 key-tiles of 32).
// grid (544 tile-chunk pairs, 4 batches), block = 2 waves = 32 q-rows.
// ---------------------------------------------------------------------------
#define KW 4
__global__ __launch_bounds__(128) void flash_kernel(const ushort_t* __restrict__ qws,
    const ushort_t* __restrict__ kws, const ushort_t* __restrict__ vt,
    ushort_t* __restrict__ opart, float* __restrict__ mpart, float* __restrict__ lpart) {
    __shared__ __align__(16) ushort_t Pw[2][16 * 40];   // stride 40 bf16 = 80 B

    int tid  = threadIdx.x;
    int wid  = tid >> 6;
    int lane = tid & 63;
    int qd   = lane >> 4;
    int lq   = lane & 15;

    int batch = blockIdx.y;
    int idx   = blockIdx.x;
    // decode (tile, chunk): group g = tile/4, tiles in group have g+1 chunks
    int g = (int)((sqrtf(2.f * idx + 1.f) - 1.f) * 0.5f);
    while (2 * (g + 1) * (g + 2) <= idx) g++;
    while (2 * g * (g + 1) > idx) g--;
    int rem  = idx - 2 * g * (g + 1);
    int tile = 4 * g + rem / (g + 1);
    int c    = rem % (g + 1);          // chunk 0..tile/4

    int q0   = tile * 32;
    int qrow = q0 + wid * 16 + lq;     // this lane's q (within batch)
    int grow = batch * T_ + qrow;

    bf16x8 qf[2];
    #pragma unroll
    for (int st = 0; st < 2; st++)
        qf[st] = *(const bf16x8*)(qws + (size_t)grow * HS_ + st * 32 + qd * 8);

    float m_run = -INFINITY, l_run = 0.f;
    f32x4 O[4];
    #pragma unroll
    for (int nt = 0; nt < 4; nt++) O[nt] = (f32x4){0.f,0.f,0.f,0.f};

    const float scale = 0.03125f;   // C^-0.5
    int kt0 = c * KW;
    int kt_end = c * KW + KW; if (kt_end > tile + 1) kt_end = tile + 1;

    ushort_t* pw = &Pw[wid][lq * 40];

    for (int kt = kt0; kt < kt_end; kt++) {
        int keybase = batch * T_ + kt * 32;

        // S^T = K . Q^T : A=K-subtile rows, B=Q^T (same regs as Q A-frag)
        f32x4 S[2];
        #pragma unroll
        for (int sub = 0; sub < 2; sub++) {
            f32x4 s = (f32x4){0.f,0.f,0.f,0.f};
            #pragma unroll
            for (int st = 0; st < 2; st++) {
                bf16x8 kf = *(const bf16x8*)(kws + (size_t)(keybase + sub * 16 + lq) * HS_ + st * 32 + qd * 8);
                s = __builtin_amdgcn_mfma_f32_16x16x32_bf16(kf, qf[st], s, 0, 0, 0);
            }
            S[sub] = s;
        }

        // V^T A-frags (independent — issue early, in flight during softmax)
        bf16x8 vf[4];
        #pragma unroll
        for (int nt = 0; nt < 4; nt++)
            vf[nt] = *(const bf16x8*)(vt + ((size_t)batch * 64 + nt * 16 + lq) * T_ + kt * 32 + qd * 8);

        // mask + scale + online softmax (q fixed per lane; keys in 8 regs + quads)
        float mx = -INFINITY;
        #pragma unroll
        for (int sub = 0; sub < 2; sub++)
            #pragma unroll
            for (int r = 0; r < 4; r++) {
                int key = kt * 32 + sub * 16 + qd * 4 + r;
                float v = (key <= qrow) ? S[sub][r] * scale : -INFINITY;
                S[sub][r] = v;
                mx = fmaxf(mx, v);
            }
        mx = fmaxf(mx, __shfl_xor(mx, 16, 64));
        mx = fmaxf(mx, __shfl_xor(mx, 32, 64));
        float m_new = fmaxf(m_run, mx);
        float alpha = __expf(m_run - m_new);
        float sum = 0.f;
        #pragma unroll
        for (int sub = 0; sub < 2; sub++)
            #pragma unroll
            for (int r = 0; r < 4; r++) {
                float p = __expf(S[sub][r] - m_new);
                S[sub][r] = p;
                sum += p;
            }
        sum += __shfl_xor(sum, 16, 64);
        sum += __shfl_xor(sum, 32, 64);
        l_run = l_run * alpha + sum;
        m_run = m_new;
        #pragma unroll
        for (int nt = 0; nt < 4; nt++)
            #pragma unroll
            for (int r = 0; r < 4; r++) O[nt][r] *= alpha;

        // P^T: C-layout -> LDS (b64 writes) -> B-layout (b128 read), per-wave
        #pragma unroll
        for (int sub = 0; sub < 2; sub++) {
            uint2 d;
            d.x = (unsigned)f2bf(S[sub][0]) | ((unsigned)f2bf(S[sub][1]) << 16);
            d.y = (unsigned)f2bf(S[sub][2]) | ((unsigned)f2bf(S[sub][3]) << 16);
            *(uint2*)(pw + sub * 16 + qd * 4) = d;
        }
        bf16x8 pf = *(const bf16x8*)(pw + qd * 8);

        // O^T += V^T . P^T
        #pragma unroll
        for (int nt = 0; nt < 4; nt++)
            O[nt] = __builtin_amdgcn_mfma_f32_16x16x32_bf16(vf[nt], pf, O[nt], 0, 0, 0);
    }

    // partials: O^T C-layout row = d = nt*16+qd*4+r, col = q = lq. bf16, 8B stores.
    #pragma unroll
    for (int nt = 0; nt < 4; nt++) {
        uint2 d;
        d.x = (unsigned)f2bf(O[nt][0]) | ((unsigned)f2bf(O[nt][1]) << 16);
        d.y = (unsigned)f2bf(O[nt][2]) | ((unsigned)f2bf(O[nt][3]) << 16);
        *(uint2*)(opart + ((size_t)c * M_ + grow) * HS_ + nt * 16 + qd * 4) = d;
    }
    if (qd == 0) {
        mpart[(size_t)c * M_ + grow] = m_run;
        lpart[(size_t)c * M_ + grow] = l_run;
    }
}

// ---------------------------------------------------------------------------
// Kernel 5: LSE combine of up to 16 chunks. 16 threads/row (4 d each).
// ---------------------------------------------------------------------------
__global__ void combine_kernel(const ushort_t* __restrict__ opart,
    const float* __restrict__ mpart, const float* __restrict__ lpart,
    float* __restrict__ out) {
    int idx = blockIdx.x * 256 + threadIdx.x;   // < 8192*16
    int row = idx >> 4;
    int d   = (idx & 15) << 2;
    int t_idx = (row & 2047) >> 5;
    int nc = t_idx / 4 + 1;

    float M = -INFINITY;
    for (int c = 0; c < nc; c++) M = fmaxf(M, mpart[(size_t)c * M_ + row]);
    float L = 0.f;
    float4 acc = make_float4(0.f, 0.f, 0.f, 0.f);
    for (int c = 0; c < nc; c++) {
        float e = __expf(mpart[(size_t)c * M_ + row] - M);
        L += lpart[(size_t)c * M_ + row] * e;
        const ushort_t* op = opart + ((size_t)c * M_ + row) * HS_ + d;
        ushort2 a = *(const ushort2*)op;
        ushort2 b = *(const ushort2*)(op + 2);
        acc.x += b2f(a.x) * e;
        acc.y += b2f(a.y) * e;
        acc.z += b2f(b.x) * e;
        acc.w += b2f(b.y) * e;
    }
    float li = 1.f / L;
    float4 o = make_float4(acc.x * li, acc.y * li, acc.z * li, acc.w * li);
    *(float4*)(out + (size_t)row * HS_ + d) = o;
}

// ---------------------------------------------------------------------------
extern "C" void kernel_launch(void* const* d_in, const int* in_sizes, int n_in,
                              void* d_out, int out_size, void* d_ws, size_t ws_size,
                              hipStream_t stream) {
    const float* x  = (const float*)d_in[0];
    const float* Wq = (const float*)d_in[1];
    const float* Wk = (const float*)d_in[2];
    const float* Wv = (const float*)d_in[3];
    float* out = (float*)d_out;

    ushort_t* wt  = (ushort_t*)d_ws;                   // 192K elems
    ushort_t* qws = wt  + (size_t)NCAT * C_;           // 8192*64
    ushort_t* kws = qws + (size_t)M_ * HS_;            // 8192*64
    ushort_t* vt  = kws + (size_t)M_ * HS_;            // 4*64*2048
    float* mpart  = (float*)(vt + (size_t)M_ * HS_);   // 16*8192
    float* lpart  = mpart + (size_t)16 * M_;           // 16*8192
    // BIG region: xb (16.8 MB, consumed by proj) then aliased by opart (16.8 MB)
    ushort_t* xb    = (ushort_t*)(lpart + (size_t)16 * M_);  // 8192*1024 bf16
    ushort_t* opart = xb;                                    // 16*8192*64 bf16 (same size)

    wconv_kernel<<<NCAT * C_ / 256, 256, 0, stream>>>(Wq, Wk, Wv, wt);
    xconv_kernel<<<M_ * C_ / (256 * 8), 256, 0, stream>>>(x, xb);
    proj_kernel<<<dim3(M_ / 32, 6), 128, 0, stream>>>(xb, wt, qws, kws, vt);
    flash_kernel<<<dim3(544, 4), 128, 0, stream>>>(qws, kws, vt, opart, mpart, lpart);
    combine_kernel<<<M_ * 16 / 256, 256, 0, stream>>>(opart, mpart, lpart, out);
}